// Round 12
// baseline (2472.852 us; speedup 1.0000x reference)
//
#include <hip/hip_runtime.h>
#include <math.h>

static constexpr int NR = 4096;   // N rows
static constexpr int DD = 512;    // feature dim

typedef __attribute__((ext_vector_type(8))) short short8v;
typedef __attribute__((ext_vector_type(4))) float floatx4;

__device__ __forceinline__ unsigned short f2bf(float f) {
    union { float f; unsigned u; } c; c.f = f;
    unsigned r = c.u + 0x7fffu + ((c.u >> 16) & 1u);   // RTNE
    return (unsigned short)(r >> 16);
}
__device__ __forceinline__ float bf2f(unsigned short h) {
    union { unsigned u; float f; } c; c.u = ((unsigned)h) << 16;
    return c.f;
}
__device__ __forceinline__ float blo(unsigned w) {
    union { unsigned u; float f; } c; c.u = w << 16; return c.f;
}
__device__ __forceinline__ float bhi(unsigned w) {
    union { unsigned u; float f; } c; c.u = w & 0xffff0000u; return c.f;
}

#define GLOAD16(gp, lp) __builtin_amdgcn_global_load_lds(                       \
    (const __attribute__((address_space(1))) void*)(gp),                        \
    (__attribute__((address_space(3))) void*)(lp), 16, 0, 0)

// ---------------------------------------------------------------------------
// NT bf16 MFMA GEMM (unchanged — verified absmax 0.0).
// ---------------------------------------------------------------------------
template<int EPI>
__global__ __launch_bounds__(256)
void ntgemm(const unsigned short* __restrict__ A, const unsigned short* __restrict__ B,
            void* __restrict__ out, int lda, int KS, int ldc, float escale)
{
    __shared__ unsigned short As[128 * 32];
    __shared__ unsigned short Bs[128 * 32];
    const int tid  = threadIdx.x;
    const int wave = tid >> 6, lane = tid & 63;
    const int bm = blockIdx.y * 128, bn = blockIdx.x * 128;
    const int wr = wave >> 1, wc = wave & 1;
    const int kBeg = blockIdx.z * KS;

    const int srow = wave * 32 + (lane >> 2);
    const int skb  = (lane & 3) * 8;
    const unsigned short* pA0 = A + (size_t)(bm + srow) * lda + kBeg + skb;
    const unsigned short* pA1 = pA0 + (size_t)16 * lda;
    const unsigned short* pB0 = B + (size_t)(bn + srow) * lda + kBeg + skb;
    const unsigned short* pB1 = pB0 + (size_t)16 * lda;
    unsigned short* lA0 = &As[wave * 1024];
    unsigned short* lA1 = &As[wave * 1024 + 512];
    unsigned short* lB0 = &Bs[wave * 1024];
    unsigned short* lB1 = &Bs[wave * 1024 + 512];

    floatx4 acc[4][4];
    #pragma unroll
    for (int i = 0; i < 4; ++i)
        #pragma unroll
        for (int j = 0; j < 4; ++j)
            acc[i][j] = (floatx4){0.f, 0.f, 0.f, 0.f};

    const int fr = lane & 15;
    const int kg = (lane >> 4) * 8;

    for (int k0 = 0; k0 < KS; k0 += 32) {
        GLOAD16(pA0 + k0, lA0);
        GLOAD16(pA1 + k0, lA1);
        GLOAD16(pB0 + k0, lB0);
        GLOAD16(pB1 + k0, lB1);
        __syncthreads();

        short8v a[4], b[4];
        #pragma unroll
        for (int i = 0; i < 4; ++i)
            a[i] = *(const short8v*)&As[(wr * 64 + i * 16 + fr) * 32 + kg];
        #pragma unroll
        for (int j = 0; j < 4; ++j)
            b[j] = *(const short8v*)&Bs[(wc * 64 + j * 16 + fr) * 32 + kg];
        #pragma unroll
        for (int i = 0; i < 4; ++i)
            #pragma unroll
            for (int j = 0; j < 4; ++j)
                acc[i][j] = __builtin_amdgcn_mfma_f32_16x16x32_bf16(a[i], b[j], acc[i][j], 0, 0, 0);
        __syncthreads();
    }

    const int r0 = (lane >> 4) * 4;
    #pragma unroll
    for (int i = 0; i < 4; ++i)
        #pragma unroll
        for (int j = 0; j < 4; ++j)
            #pragma unroll
            for (int r = 0; r < 4; ++r) {
                const int m = bm + wr * 64 + i * 16 + r0 + r;
                const int n = bn + wc * 64 + j * 16 + fr;
                float x = acc[i][j][r];
                if (EPI == 1) x = __expf(escale * x);
                if (EPI <= 1) ((unsigned short*)out)[(size_t)m * ldc + n] = f2bf(x);
                else ((float*)out)[(size_t)blockIdx.z * (512 * 512) + (size_t)m * ldc + n] = x;
            }
}

__global__ void convert_bf16(const float* __restrict__ in, unsigned short* __restrict__ out, int n4)
{
    const int i = blockIdx.x * 256 + threadIdx.x;
    if (i < n4) {
        const float4 v = ((const float4*)in)[i];
        ushort4 o;
        o.x = f2bf(v.x); o.y = f2bf(v.y); o.z = f2bf(v.z); o.w = f2bf(v.w);
        ((ushort4*)out)[i] = o;
    }
}

// XT[d][i] = bf16( s[i] * X[i][d] )
__global__ __launch_bounds__(256)
void scale_transpose(const float* __restrict__ X, const float* __restrict__ s,
                     unsigned short* __restrict__ XT)
{
    __shared__ float tile[64][65];
    const int i0 = blockIdx.x * 64;
    const int d0 = blockIdx.y * 64;
    const int t = threadIdx.x, c = t & 63, r4 = t >> 6;
    #pragma unroll
    for (int rr = 0; rr < 64; rr += 4) {
        const int i = i0 + rr + r4;
        tile[rr + r4][c] = X[(size_t)i * DD + d0 + c] * s[i];
    }
    __syncthreads();
    #pragma unroll
    for (int dd = 0; dd < 64; dd += 4) {
        const int d = dd + r4;
        XT[(size_t)(d0 + d) * NR + i0 + c] = f2bf(tile[c][d]);
    }
}

__global__ __launch_bounds__(256)
void amat_update(const float* __restrict__ Dacc, float* __restrict__ Af,
                 unsigned short* __restrict__ ATb)
{
    __shared__ float tile[64][65];
    const int e0 = blockIdx.x * 64, d0 = blockIdx.y * 64;
    const int t = threadIdx.x, c = t & 63, r4 = t >> 6;
    #pragma unroll
    for (int rr = 0; rr < 64; rr += 4) {
        const int e = e0 + rr + r4;
        const size_t idx = (size_t)e * DD + d0 + c;
        float ssum = 0.f;
        #pragma unroll
        for (int z = 0; z < 8; ++z) ssum += Dacc[(size_t)z * (512 * 512) + idx];
        const float nv = Af[idx] + 1e-4f * ssum;
        Af[idx] = nv;
        tile[rr + r4][c] = nv;
    }
    __syncthreads();
    #pragma unroll
    for (int dd = 0; dd < 64; dd += 4) {
        const int d = dd + r4;
        ATb[(size_t)(d0 + d) * DD + e0 + c] = f2bf(tile[c][d]);
    }
}

__global__ void init_amat(float* __restrict__ Af)
{
    const int i = blockIdx.x * 256 + threadIdx.x;
    if (i < DD * DD) Af[i] = (i / DD == i % DD) ? 1.0f : 0.0f;
}

__global__ void fill_kernel(float* __restrict__ p, int n, float val)
{
    const int i = blockIdx.x * 256 + threadIdx.x;
    if (i < n) p[i] = val;
}

// u[row] = 1 / sum_j K[row][j] * v[j]   (initial softmax denominators)
__global__ __launch_bounds__(256)
void rowmv_recip_b(const unsigned short* __restrict__ Kb, const float* __restrict__ v,
                   float* __restrict__ u)
{
    const int row = blockIdx.x * 4 + (threadIdx.x >> 6);
    const int lane = threadIdx.x & 63;
    const unsigned short* Kr = Kb + (size_t)row * NR;
    float s = 0.f;
    #pragma unroll
    for (int it = 0; it < 8; ++it) {
        const int j = it * 512 + lane * 8;
        const uint4 kw = *(const uint4*)&Kr[j];
        const float4 va = *(const float4*)&v[j];
        const float4 vb = *(const float4*)&v[j + 4];
        s += blo(kw.x) * va.x + bhi(kw.x) * va.y + blo(kw.y) * va.z + bhi(kw.y) * va.w
           + blo(kw.z) * vb.x + bhi(kw.z) * vb.y + blo(kw.w) * vb.z + bhi(kw.w) * vb.w;
    }
    #pragma unroll
    for (int off = 32; off; off >>= 1) s += __shfl_xor(s, off);
    if (lane == 0) u[row] = 1.0f / s;
}

// ---------------------------------------------------------------------------
// Cooperative persistent Sinkhorn — EXACT round-7 verified structure
// (RMW-spin barrier, 10 gens/launch, baseGen = 10*it). Single change vs
// round 7: spin cadence s_sleep(8) -> s_sleep(64) to cut spin-RMW pressure
// on the counter line ~8x (arrivals queue behind spin RMWs; both remain
// RMWs, so cross-XCD coherence-point visibility is preserved).
// ---------------------------------------------------------------------------
__device__ __forceinline__ int swz(int r, int c2) {   // byte offset into band
    return r * 8192 + (c2 ^ (((c2 >> 7) & 7) << 4));
}

__device__ __forceinline__ void grid_barrier(int* bar, int gen)
{
    __syncthreads();
    if (threadIdx.x == 0) {
        __threadfence();                       // release: flush block's writes
        atomicAdd(bar, 1);
        while (atomicAdd(bar, 0) < gen * 256)  // monotonic counter, no reset
            __builtin_amdgcn_s_sleep(64);      // ~4096 clk between probes
        __threadfence();                       // acquire: invalidate stale lines
    }
    __syncthreads();
}

__global__ __launch_bounds__(256, 1)
void sinkhorn5(const unsigned short* __restrict__ Kb,
               float* __restrict__ ug, float* __restrict__ vg,
               float* __restrict__ Pp, int* __restrict__ bar,
               const int* __restrict__ labels, float* __restrict__ out,
               int baseGen, int doLoss)
{
    __shared__ unsigned short Ks[16 * 4096];   // 128 KiB swizzled band
    __shared__ float red[4][16];
    __shared__ float uL[16];
    __shared__ float lossRed[16];

    const int b = blockIdx.x;
    const int t = threadIdx.x;
    const int wave = t >> 6, lane = t & 63;

    // ---- stage band: rows [16b, 16b+16) ----
    const char* gK = (const char*)(Kb + (size_t)b * 16 * NR);
    char* lK = (char*)Ks;
    #pragma unroll
    for (int l = 0; l < 32; ++l) {
        const int ci = l * 256 + t;           // 16B chunk id (8192 total)
        const int r  = ci >> 9;               // 512 chunks per row
        const int c2 = (ci & 511) * 16;       // byte offset within row
        const uint4 d = *(const uint4*)(gK + r * 8192 + c2);
        *(uint4*)(lK + swz(r, c2)) = d;
    }
    __syncthreads();

    // thread t owns cols [16t, 16t+16): precompute swizzled chunk offsets
    const int cb   = t * 32;                  // byte base of col chunk
    const int swc0 = cb ^ (((cb >> 7) & 7) << 4);
    const int cb1  = cb + 16;
    const int swc1 = cb1 ^ (((cb1 >> 7) & 7) << 4);

    float vr[16];
    #pragma unroll
    for (int c = 0; c < 16; ++c) vr[c] = 1.0f;

    for (int it = 0; it < 5; ++it) {
        // ---- u-phase: rowpart over own cols, then block-reduce per row ----
        float rp[16];
        #pragma unroll
        for (int r = 0; r < 16; ++r) {
            const uint4 A = *(const uint4*)(lK + r * 8192 + swc0);
            const uint4 B = *(const uint4*)(lK + r * 8192 + swc1);
            rp[r] = blo(A.x)*vr[0]  + bhi(A.x)*vr[1]  + blo(A.y)*vr[2]  + bhi(A.y)*vr[3]
                  + blo(A.z)*vr[4]  + bhi(A.z)*vr[5]  + blo(A.w)*vr[6]  + bhi(A.w)*vr[7]
                  + blo(B.x)*vr[8]  + bhi(B.x)*vr[9]  + blo(B.y)*vr[10] + bhi(B.y)*vr[11]
                  + blo(B.z)*vr[12] + bhi(B.z)*vr[13] + blo(B.w)*vr[14] + bhi(B.w)*vr[15];
        }
        #pragma unroll
        for (int r = 0; r < 16; ++r) {
            float s = rp[r];
            #pragma unroll
            for (int off = 32; off; off >>= 1) s += __shfl_xor(s, off);
            if (lane == 0) red[wave][r] = s;
        }
        __syncthreads();
        if (t < 16) uL[t] = 1.0f / (red[0][t] + red[1][t] + red[2][t] + red[3][t]);
        __syncthreads();

        // ---- v-phase: col partials over the block's 16 rows ----
        float cp[16];
        #pragma unroll
        for (int c = 0; c < 16; ++c) cp[c] = 0.f;
        #pragma unroll
        for (int r = 0; r < 16; ++r) {
            const float ur = uL[r];
            const uint4 A = *(const uint4*)(lK + r * 8192 + swc0);
            const uint4 B = *(const uint4*)(lK + r * 8192 + swc1);
            cp[0]  += ur * blo(A.x); cp[1]  += ur * bhi(A.x);
            cp[2]  += ur * blo(A.y); cp[3]  += ur * bhi(A.y);
            cp[4]  += ur * blo(A.z); cp[5]  += ur * bhi(A.z);
            cp[6]  += ur * blo(A.w); cp[7]  += ur * bhi(A.w);
            cp[8]  += ur * blo(B.x); cp[9]  += ur * bhi(B.x);
            cp[10] += ur * blo(B.y); cp[11] += ur * bhi(B.y);
            cp[12] += ur * blo(B.z); cp[13] += ur * bhi(B.z);
            cp[14] += ur * blo(B.w); cp[15] += ur * bhi(B.w);
        }
        {   // write partial row P[b][16t .. 16t+16)
            float4* pw = (float4*)(Pp + (size_t)b * NR + t * 16);
            pw[0] = make_float4(cp[0],  cp[1],  cp[2],  cp[3]);
            pw[1] = make_float4(cp[4],  cp[5],  cp[6],  cp[7]);
            pw[2] = make_float4(cp[8],  cp[9],  cp[10], cp[11]);
            pw[3] = make_float4(cp[12], cp[13], cp[14], cp[15]);
        }
        grid_barrier(bar, baseGen + it * 2 + 1);

        // ---- v-reduce: block b reduces cols [16b, 16b+16) over 256 partials
        {
            const float4* pr = (const float4*)(Pp + (size_t)t * NR + b * 16);
            const float4 q0 = pr[0], q1 = pr[1], q2 = pr[2], q3 = pr[3];
            float val[16] = { q0.x, q0.y, q0.z, q0.w, q1.x, q1.y, q1.z, q1.w,
                              q2.x, q2.y, q2.z, q2.w, q3.x, q3.y, q3.z, q3.w };
            #pragma unroll
            for (int c = 0; c < 16; ++c) {
                float s = val[c];
                #pragma unroll
                for (int off = 32; off; off >>= 1) s += __shfl_xor(s, off);
                if (lane == 0) red[wave][c] = s;
            }
            __syncthreads();
            if (t < 16)
                vg[b * 16 + t] = 1.0f / (red[0][t] + red[1][t] + red[2][t] + red[3][t]);
        }
        grid_barrier(bar, baseGen + it * 2 + 2);

        // ---- reload own v slice ----
        const float4* vv = (const float4*)(vg + t * 16);
        const float4 v0 = vv[0], v1 = vv[1], v2 = vv[2], v3 = vv[3];
        vr[0]=v0.x; vr[1]=v0.y; vr[2]=v0.z; vr[3]=v0.w;
        vr[4]=v1.x; vr[5]=v1.y; vr[6]=v1.z; vr[7]=v1.w;
        vr[8]=v2.x; vr[9]=v2.y; vr[10]=v2.z; vr[11]=v2.w;
        vr[12]=v3.x; vr[13]=v3.y; vr[14]=v3.z; vr[15]=v3.w;
    }

    // ---- publish final u ----
    if (t < 16) ug[b * 16 + t] = uL[t];

    if (doLoss) {
        // loss_i = log(sum_j exp(u_i K_ij v_j)) - u_i K[i,y] v[y]
        #pragma unroll
        for (int r = 0; r < 16; ++r) {
            const float ur = uL[r];
            const uint4 A = *(const uint4*)(lK + r * 8192 + swc0);
            const uint4 B = *(const uint4*)(lK + r * 8192 + swc1);
            float s = __expf(ur*blo(A.x)*vr[0])  + __expf(ur*bhi(A.x)*vr[1])
                    + __expf(ur*blo(A.y)*vr[2])  + __expf(ur*bhi(A.y)*vr[3])
                    + __expf(ur*blo(A.z)*vr[4])  + __expf(ur*bhi(A.z)*vr[5])
                    + __expf(ur*blo(A.w)*vr[6])  + __expf(ur*bhi(A.w)*vr[7])
                    + __expf(ur*blo(B.x)*vr[8])  + __expf(ur*bhi(B.x)*vr[9])
                    + __expf(ur*blo(B.y)*vr[10]) + __expf(ur*bhi(B.y)*vr[11])
                    + __expf(ur*blo(B.z)*vr[12]) + __expf(ur*bhi(B.z)*vr[13])
                    + __expf(ur*blo(B.w)*vr[14]) + __expf(ur*bhi(B.w)*vr[15]);
            #pragma unroll
            for (int off = 32; off; off >>= 1) s += __shfl_xor(s, off);
            if (lane == 0) red[wave][r] = s;
        }
        __syncthreads();
        if (t < 16) {
            const float s = red[0][t] + red[1][t] + red[2][t] + red[3][t];
            const int row = b * 16 + t;
            const int y = labels[row];
            const int c2 = y * 2;
            const unsigned short kv = *(const unsigned short*)(lK + swz(t, c2));
            const float py = uL[t] * bf2f(kv) * vg[y];
            lossRed[t] = logf(s) - py;
        }
        __syncthreads();
        if (t == 0) {
            float s = 0.f;
            #pragma unroll
            for (int r = 0; r < 16; ++r) s += lossRed[r];
            atomicAdd(out, s * (1.0f / NR));
        }
    }
}

extern "C" void kernel_launch(void* const* d_in, const int* in_sizes, int n_in,
                              void* d_out, int out_size, void* d_ws, size_t ws_size,
                              hipStream_t stream)
{
    const float* img    = (const float*)d_in[0];   // [4096,512]
    const float* txt    = (const float*)d_in[1];   // [4096,512]
    const int*   labels = (const int*)d_in[2];     // [4096]
    float* out = (float*)d_out;

    char* ws = (char*)d_ws;
    unsigned short* K_b    = (unsigned short*)(ws);                        // 32 MiB
    unsigned short* img_b  = (unsigned short*)(ws + ((size_t)32 << 20));   //  4 MiB
    unsigned short* txt_b  = (unsigned short*)(ws + ((size_t)36 << 20));   //  4 MiB
    unsigned short* vtxtT  = (unsigned short*)(ws + ((size_t)40 << 20));   //  4 MiB
    unsigned short* uimgT  = (unsigned short*)(ws + ((size_t)44 << 20));   //  4 MiB
    unsigned short* NB2T   = (unsigned short*)(ws + ((size_t)48 << 20));   //  4 MiB
    unsigned short* NB_b   = (unsigned short*)(ws + ((size_t)52 << 20));   //  4 MiB
    unsigned short* AmatT  = (unsigned short*)(ws + ((size_t)56 << 20));   // 0.5 MiB
    float* Amat_f          = (float*)(ws + ((size_t)57 << 20));            //  1 MiB
    float* Dacc            = (float*)(ws + ((size_t)58 << 20));            //  8 MiB
    float* Pbuf            = Dacc;   // alias: Dacc dead once amat_update ran
    float* u               = (float*)(ws + ((size_t)66 << 20));
    float* v               = (float*)(ws + ((size_t)66 << 20) + (16 << 10));
    int*   bar             = (int*)  (ws + ((size_t)66 << 20) + (32 << 10));

    const dim3 blk(256);
    const dim3 gNN(32, 32);
    const dim3 gG2(32, 4);
    const dim3 gG3(4, 4, 8);
    const dim3 gG4(4, 32);
    const dim3 gST(64, 8);

    convert_bf16<<<2048, blk, 0, stream>>>(img, img_b, NR * DD / 4);
    convert_bf16<<<2048, blk, 0, stream>>>(txt, txt_b, NR * DD / 4);
    hipMemsetAsync(bar, 0, sizeof(int), stream);
    hipMemsetAsync(out, 0, sizeof(float), stream);

    // K = exp(100 * img.txt^T); u = 1/rowsum (exact row softmax); A = I
    ntgemm<1><<<gNN, blk, 0, stream>>>(img_b, txt_b, K_b, DD, DD, NR, 100.0f);
    fill_kernel<<<16, blk, 0, stream>>>(v, NR, 1.0f);
    rowmv_recip_b<<<NR / 4, blk, 0, stream>>>(K_b, v, u);
    init_amat<<<DD * DD / 256, blk, 0, stream>>>(Amat_f);

    for (int it = 0; it < 5; ++it) {
        scale_transpose<<<gST, blk, 0, stream>>>(txt, v, vtxtT);
        ntgemm<0><<<gG2, blk, 0, stream>>>(vtxtT, K_b, NB2T, NR, NR, NR, 0.f);
        scale_transpose<<<gST, blk, 0, stream>>>(img, u, uimgT);
        ntgemm<2><<<gG3, blk, 0, stream>>>(uimgT, NB2T, Dacc, NR, NR / 8, DD, 0.f);
        amat_update<<<dim3(8, 8), blk, 0, stream>>>(Dacc, Amat_f, AmatT);
        ntgemm<0><<<gG4, blk, 0, stream>>>(img_b, AmatT, NB_b, DD, DD, DD, 0.f);
        ntgemm<1><<<gNN, blk, 0, stream>>>(NB_b, txt_b, K_b, DD, DD, NR, -1.0f);

        // cooperative persistent sinkhorn (round-7 verified: 10 gens/launch)
        int baseGen = it * 10;
        int doLoss  = (it == 4) ? 1 : 0;
        const unsigned short* Kc = K_b;
        const int* lab = labels;
        void* args[] = { (void*)&Kc, (void*)&u, (void*)&v, (void*)&Pbuf,
                         (void*)&bar, (void*)&lab, (void*)&out,
                         (void*)&baseGen, (void*)&doLoss };
        hipLaunchCooperativeKernel((void*)sinkhorn5, dim3(256), blk, args, 0, stream);
    }
}

// Round 14
// 2031.299 us; speedup vs baseline: 1.2174x; 1.2174x over previous
//
#include <hip/hip_runtime.h>
#include <math.h>

static constexpr int NR = 4096;   // N rows
static constexpr int DD = 512;    // feature dim

typedef __attribute__((ext_vector_type(8))) short short8v;
typedef __attribute__((ext_vector_type(4))) float floatx4;

__device__ __forceinline__ unsigned short f2bf(float f) {
    union { float f; unsigned u; } c; c.f = f;
    unsigned r = c.u + 0x7fffu + ((c.u >> 16) & 1u);   // RTNE
    return (unsigned short)(r >> 16);
}
__device__ __forceinline__ float bf2f(unsigned short h) {
    union { unsigned u; float f; } c; c.u = ((unsigned)h) << 16;
    return c.f;
}
__device__ __forceinline__ float blo(unsigned w) {
    union { unsigned u; float f; } c; c.u = w << 16; return c.f;
}
__device__ __forceinline__ float bhi(unsigned w) {
    union { unsigned u; float f; } c; c.u = w & 0xffff0000u; return c.f;
}

#define GLOAD16(gp, lp) __builtin_amdgcn_global_load_lds(                       \
    (const __attribute__((address_space(1))) void*)(gp),                        \
    (__attribute__((address_space(3))) void*)(lp), 16, 0, 0)

// ---------------------------------------------------------------------------
// NT bf16 MFMA GEMM (unchanged — verified absmax 0.0).
// ---------------------------------------------------------------------------
template<int EPI>
__global__ __launch_bounds__(256)
void ntgemm(const unsigned short* __restrict__ A, const unsigned short* __restrict__ B,
            void* __restrict__ out, int lda, int KS, int ldc, float escale)
{
    __shared__ unsigned short As[128 * 32];
    __shared__ unsigned short Bs[128 * 32];
    const int tid  = threadIdx.x;
    const int wave = tid >> 6, lane = tid & 63;
    const int bm = blockIdx.y * 128, bn = blockIdx.x * 128;
    const int wr = wave >> 1, wc = wave & 1;
    const int kBeg = blockIdx.z * KS;

    const int srow = wave * 32 + (lane >> 2);
    const int skb  = (lane & 3) * 8;
    const unsigned short* pA0 = A + (size_t)(bm + srow) * lda + kBeg + skb;
    const unsigned short* pA1 = pA0 + (size_t)16 * lda;
    const unsigned short* pB0 = B + (size_t)(bn + srow) * lda + kBeg + skb;
    const unsigned short* pB1 = pB0 + (size_t)16 * lda;
    unsigned short* lA0 = &As[wave * 1024];
    unsigned short* lA1 = &As[wave * 1024 + 512];
    unsigned short* lB0 = &Bs[wave * 1024];
    unsigned short* lB1 = &Bs[wave * 1024 + 512];

    floatx4 acc[4][4];
    #pragma unroll
    for (int i = 0; i < 4; ++i)
        #pragma unroll
        for (int j = 0; j < 4; ++j)
            acc[i][j] = (floatx4){0.f, 0.f, 0.f, 0.f};

    const int fr = lane & 15;
    const int kg = (lane >> 4) * 8;

    for (int k0 = 0; k0 < KS; k0 += 32) {
        GLOAD16(pA0 + k0, lA0);
        GLOAD16(pA1 + k0, lA1);
        GLOAD16(pB0 + k0, lB0);
        GLOAD16(pB1 + k0, lB1);
        __syncthreads();

        short8v a[4], b[4];
        #pragma unroll
        for (int i = 0; i < 4; ++i)
            a[i] = *(const short8v*)&As[(wr * 64 + i * 16 + fr) * 32 + kg];
        #pragma unroll
        for (int j = 0; j < 4; ++j)
            b[j] = *(const short8v*)&Bs[(wc * 64 + j * 16 + fr) * 32 + kg];
        #pragma unroll
        for (int i = 0; i < 4; ++i)
            #pragma unroll
            for (int j = 0; j < 4; ++j)
                acc[i][j] = __builtin_amdgcn_mfma_f32_16x16x32_bf16(a[i], b[j], acc[i][j], 0, 0, 0);
        __syncthreads();
    }

    const int r0 = (lane >> 4) * 4;
    #pragma unroll
    for (int i = 0; i < 4; ++i)
        #pragma unroll
        for (int j = 0; j < 4; ++j)
            #pragma unroll
            for (int r = 0; r < 4; ++r) {
                const int m = bm + wr * 64 + i * 16 + r0 + r;
                const int n = bn + wc * 64 + j * 16 + fr;
                float x = acc[i][j][r];
                if (EPI == 1) x = __expf(escale * x);
                if (EPI <= 1) ((unsigned short*)out)[(size_t)m * ldc + n] = f2bf(x);
                else ((float*)out)[(size_t)blockIdx.z * (512 * 512) + (size_t)m * ldc + n] = x;
            }
}

__global__ void convert_bf16(const float* __restrict__ in, unsigned short* __restrict__ out, int n4)
{
    const int i = blockIdx.x * 256 + threadIdx.x;
    if (i < n4) {
        const float4 v = ((const float4*)in)[i];
        ushort4 o;
        o.x = f2bf(v.x); o.y = f2bf(v.y); o.z = f2bf(v.z); o.w = f2bf(v.w);
        ((ushort4*)out)[i] = o;
    }
}

// XT[d][i] = bf16( s[i] * X[i][d] )
__global__ __launch_bounds__(256)
void scale_transpose(const float* __restrict__ X, const float* __restrict__ s,
                     unsigned short* __restrict__ XT)
{
    __shared__ float tile[64][65];
    const int i0 = blockIdx.x * 64;
    const int d0 = blockIdx.y * 64;
    const int t = threadIdx.x, c = t & 63, r4 = t >> 6;
    #pragma unroll
    for (int rr = 0; rr < 64; rr += 4) {
        const int i = i0 + rr + r4;
        tile[rr + r4][c] = X[(size_t)i * DD + d0 + c] * s[i];
    }
    __syncthreads();
    #pragma unroll
    for (int dd = 0; dd < 64; dd += 4) {
        const int d = dd + r4;
        XT[(size_t)(d0 + d) * NR + i0 + c] = f2bf(tile[c][d]);
    }
}

__global__ __launch_bounds__(256)
void amat_update(const float* __restrict__ Dacc, float* __restrict__ Af,
                 unsigned short* __restrict__ ATb)
{
    __shared__ float tile[64][65];
    const int e0 = blockIdx.x * 64, d0 = blockIdx.y * 64;
    const int t = threadIdx.x, c = t & 63, r4 = t >> 6;
    #pragma unroll
    for (int rr = 0; rr < 64; rr += 4) {
        const int e = e0 + rr + r4;
        const size_t idx = (size_t)e * DD + d0 + c;
        float ssum = 0.f;
        #pragma unroll
        for (int z = 0; z < 8; ++z) ssum += Dacc[(size_t)z * (512 * 512) + idx];
        const float nv = Af[idx] + 1e-4f * ssum;
        Af[idx] = nv;
        tile[rr + r4][c] = nv;
    }
    __syncthreads();
    #pragma unroll
    for (int dd = 0; dd < 64; dd += 4) {
        const int d = dd + r4;
        ATb[(size_t)(d0 + d) * DD + e0 + c] = f2bf(tile[c][d]);
    }
}

__global__ void init_amat(float* __restrict__ Af)
{
    const int i = blockIdx.x * 256 + threadIdx.x;
    if (i < DD * DD) Af[i] = (i / DD == i % DD) ? 1.0f : 0.0f;
}

__global__ void fill_kernel(float* __restrict__ p, int n, float val)
{
    const int i = blockIdx.x * 256 + threadIdx.x;
    if (i < n) p[i] = val;
}

// u[row] = 1 / sum_j K[row][j] * v[j]   (initial softmax denominators)
__global__ __launch_bounds__(256)
void rowmv_recip_b(const unsigned short* __restrict__ Kb, const float* __restrict__ v,
                   float* __restrict__ u)
{
    const int row = blockIdx.x * 4 + (threadIdx.x >> 6);
    const int lane = threadIdx.x & 63;
    const unsigned short* Kr = Kb + (size_t)row * NR;
    float s = 0.f;
    #pragma unroll
    for (int it = 0; it < 8; ++it) {
        const int j = it * 512 + lane * 8;
        const uint4 kw = *(const uint4*)&Kr[j];
        const float4 va = *(const float4*)&v[j];
        const float4 vb = *(const float4*)&v[j + 4];
        s += blo(kw.x) * va.x + bhi(kw.x) * va.y + blo(kw.y) * va.z + bhi(kw.y) * va.w
           + blo(kw.z) * vb.x + bhi(kw.z) * vb.y + blo(kw.w) * vb.z + bhi(kw.w) * vb.w;
    }
    #pragma unroll
    for (int off = 32; off; off >>= 1) s += __shfl_xor(s, off);
    if (lane == 0) u[row] = 1.0f / s;
}

// ---------------------------------------------------------------------------
// Cooperative persistent Sinkhorn. Round-12 structure; barrier internals
// replaced by a HIERARCHICAL 2-level barrier (all probes are RMWs — plain
// loads are not cross-XCD safe, proven round 10). 8 groups x 32 blocks:
//   arrive:   fetch_add grp[b>>5]       (32 adders/line, 0 spinners)
//   grp-last: fetch_add root; last-of-8 completes, others RMW-spin (<=7)
//   release:  grp-last fetch_add rel[g]; 31 blocks RMW-spin on rel[g]
// Max spinners per line drops 256 -> 31, cutting the RMW FIFO queue wait
// that round 12 proved is sleep-interval-insensitive.
// ---------------------------------------------------------------------------
__device__ __forceinline__ int swz(int r, int c2) {   // byte offset into band
    return r * 8192 + (c2 ^ (((c2 >> 7) & 7) << 4));
}

// bar layout: grp[g]=bar[g*32], root=bar[8*32], rel[g]=bar[(9+g)*32]
// (one 128B line per counter; monotonic, never reset within a call)
__device__ __forceinline__ void grid_barrier(int* bar, int gen)
{
    __syncthreads();
    if (threadIdx.x == 0) {
        const int g = blockIdx.x >> 5;
        int* grp  = bar + g * 32;
        int* root = bar + 8 * 32;
        int* rel  = bar + (9 + g) * 32;
        __threadfence();                          // release: flush block's writes
        const int old = atomicAdd(grp, 1);
        if (old == gen * 32 - 1) {                // unique group-last
            const int rold = atomicAdd(root, 1);
            if (rold != gen * 8 - 1) {            // not the global completer
                while (atomicAdd(root, 0) < gen * 8)
                    __builtin_amdgcn_s_sleep(16);
            }
            atomicAdd(rel, 1);                    // release own group
        }
        while (atomicAdd(rel, 0) < gen)
            __builtin_amdgcn_s_sleep(16);
        __threadfence();                          // acquire
    }
    __syncthreads();
}

__global__ __launch_bounds__(256, 1)
void sinkhorn5(const unsigned short* __restrict__ Kb,
               float* __restrict__ ug, float* __restrict__ vg,
               float* __restrict__ Pp, int* __restrict__ bar,
               const int* __restrict__ labels, float* __restrict__ out,
               int baseGen, int doLoss)
{
    __shared__ unsigned short Ks[16 * 4096];   // 128 KiB swizzled band
    __shared__ float red[4][16];
    __shared__ float uL[16];
    __shared__ float lossRed[16];

    const int b = blockIdx.x;
    const int t = threadIdx.x;
    const int wave = t >> 6, lane = t & 63;

    // ---- stage band: rows [16b, 16b+16) ----
    const char* gK = (const char*)(Kb + (size_t)b * 16 * NR);
    char* lK = (char*)Ks;
    #pragma unroll
    for (int l = 0; l < 32; ++l) {
        const int ci = l * 256 + t;           // 16B chunk id (8192 total)
        const int r  = ci >> 9;               // 512 chunks per row
        const int c2 = (ci & 511) * 16;       // byte offset within row
        const uint4 d = *(const uint4*)(gK + r * 8192 + c2);
        *(uint4*)(lK + swz(r, c2)) = d;
    }
    __syncthreads();

    // thread t owns cols [16t, 16t+16): precompute swizzled chunk offsets
    const int cb   = t * 32;                  // byte base of col chunk
    const int swc0 = cb ^ (((cb >> 7) & 7) << 4);
    const int cb1  = cb + 16;
    const int swc1 = cb1 ^ (((cb1 >> 7) & 7) << 4);

    float vr[16];
    #pragma unroll
    for (int c = 0; c < 16; ++c) vr[c] = 1.0f;

    for (int it = 0; it < 5; ++it) {
        // ---- u-phase: rowpart over own cols, then block-reduce per row ----
        float rp[16];
        #pragma unroll
        for (int r = 0; r < 16; ++r) {
            const uint4 A = *(const uint4*)(lK + r * 8192 + swc0);
            const uint4 B = *(const uint4*)(lK + r * 8192 + swc1);
            rp[r] = blo(A.x)*vr[0]  + bhi(A.x)*vr[1]  + blo(A.y)*vr[2]  + bhi(A.y)*vr[3]
                  + blo(A.z)*vr[4]  + bhi(A.z)*vr[5]  + blo(A.w)*vr[6]  + bhi(A.w)*vr[7]
                  + blo(B.x)*vr[8]  + bhi(B.x)*vr[9]  + blo(B.y)*vr[10] + bhi(B.y)*vr[11]
                  + blo(B.z)*vr[12] + bhi(B.z)*vr[13] + blo(B.w)*vr[14] + bhi(B.w)*vr[15];
        }
        #pragma unroll
        for (int r = 0; r < 16; ++r) {
            float s = rp[r];
            #pragma unroll
            for (int off = 32; off; off >>= 1) s += __shfl_xor(s, off);
            if (lane == 0) red[wave][r] = s;
        }
        __syncthreads();
        if (t < 16) uL[t] = 1.0f / (red[0][t] + red[1][t] + red[2][t] + red[3][t]);
        __syncthreads();

        // ---- v-phase: col partials over the block's 16 rows ----
        float cp[16];
        #pragma unroll
        for (int c = 0; c < 16; ++c) cp[c] = 0.f;
        #pragma unroll
        for (int r = 0; r < 16; ++r) {
            const float ur = uL[r];
            const uint4 A = *(const uint4*)(lK + r * 8192 + swc0);
            const uint4 B = *(const uint4*)(lK + r * 8192 + swc1);
            cp[0]  += ur * blo(A.x); cp[1]  += ur * bhi(A.x);
            cp[2]  += ur * blo(A.y); cp[3]  += ur * bhi(A.y);
            cp[4]  += ur * blo(A.z); cp[5]  += ur * bhi(A.z);
            cp[6]  += ur * blo(A.w); cp[7]  += ur * bhi(A.w);
            cp[8]  += ur * blo(B.x); cp[9]  += ur * bhi(B.x);
            cp[10] += ur * blo(B.y); cp[11] += ur * bhi(B.y);
            cp[12] += ur * blo(B.z); cp[13] += ur * bhi(B.z);
            cp[14] += ur * blo(B.w); cp[15] += ur * bhi(B.w);
        }
        {   // write partial row P[b][16t .. 16t+16)
            float4* pw = (float4*)(Pp + (size_t)b * NR + t * 16);
            pw[0] = make_float4(cp[0],  cp[1],  cp[2],  cp[3]);
            pw[1] = make_float4(cp[4],  cp[5],  cp[6],  cp[7]);
            pw[2] = make_float4(cp[8],  cp[9],  cp[10], cp[11]);
            pw[3] = make_float4(cp[12], cp[13], cp[14], cp[15]);
        }
        grid_barrier(bar, baseGen + it * 2 + 1);

        // ---- v-reduce: block b reduces cols [16b, 16b+16) over 256 partials
        {
            const float4* pr = (const float4*)(Pp + (size_t)t * NR + b * 16);
            const float4 q0 = pr[0], q1 = pr[1], q2 = pr[2], q3 = pr[3];
            float val[16] = { q0.x, q0.y, q0.z, q0.w, q1.x, q1.y, q1.z, q1.w,
                              q2.x, q2.y, q2.z, q2.w, q3.x, q3.y, q3.z, q3.w };
            #pragma unroll
            for (int c = 0; c < 16; ++c) {
                float s = val[c];
                #pragma unroll
                for (int off = 32; off; off >>= 1) s += __shfl_xor(s, off);
                if (lane == 0) red[wave][c] = s;
            }
            __syncthreads();
            if (t < 16)
                vg[b * 16 + t] = 1.0f / (red[0][t] + red[1][t] + red[2][t] + red[3][t]);
        }
        grid_barrier(bar, baseGen + it * 2 + 2);

        // ---- reload own v slice ----
        const float4* vv = (const float4*)(vg + t * 16);
        const float4 v0 = vv[0], v1 = vv[1], v2 = vv[2], v3 = vv[3];
        vr[0]=v0.x; vr[1]=v0.y; vr[2]=v0.z; vr[3]=v0.w;
        vr[4]=v1.x; vr[5]=v1.y; vr[6]=v1.z; vr[7]=v1.w;
        vr[8]=v2.x; vr[9]=v2.y; vr[10]=v2.z; vr[11]=v2.w;
        vr[12]=v3.x; vr[13]=v3.y; vr[14]=v3.z; vr[15]=v3.w;
    }

    // ---- publish final u ----
    if (t < 16) ug[b * 16 + t] = uL[t];

    if (doLoss) {
        // loss_i = log(sum_j exp(u_i K_ij v_j)) - u_i K[i,y] v[y]
        #pragma unroll
        for (int r = 0; r < 16; ++r) {
            const float ur = uL[r];
            const uint4 A = *(const uint4*)(lK + r * 8192 + swc0);
            const uint4 B = *(const uint4*)(lK + r * 8192 + swc1);
            float s = __expf(ur*blo(A.x)*vr[0])  + __expf(ur*bhi(A.x)*vr[1])
                    + __expf(ur*blo(A.y)*vr[2])  + __expf(ur*bhi(A.y)*vr[3])
                    + __expf(ur*blo(A.z)*vr[4])  + __expf(ur*bhi(A.z)*vr[5])
                    + __expf(ur*blo(A.w)*vr[6])  + __expf(ur*bhi(A.w)*vr[7])
                    + __expf(ur*blo(B.x)*vr[8])  + __expf(ur*bhi(B.x)*vr[9])
                    + __expf(ur*blo(B.y)*vr[10]) + __expf(ur*bhi(B.y)*vr[11])
                    + __expf(ur*blo(B.z)*vr[12]) + __expf(ur*bhi(B.z)*vr[13])
                    + __expf(ur*blo(B.w)*vr[14]) + __expf(ur*bhi(B.w)*vr[15]);
            #pragma unroll
            for (int off = 32; off; off >>= 1) s += __shfl_xor(s, off);
            if (lane == 0) red[wave][r] = s;
        }
        __syncthreads();
        if (t < 16) {
            const float s = red[0][t] + red[1][t] + red[2][t] + red[3][t];
            const int row = b * 16 + t;
            const int y = labels[row];
            const int c2 = y * 2;
            const unsigned short kv = *(const unsigned short*)(lK + swz(t, c2));
            const float py = uL[t] * bf2f(kv) * vg[y];
            lossRed[t] = logf(s) - py;
        }
        __syncthreads();
        if (t == 0) {
            float s = 0.f;
            #pragma unroll
            for (int r = 0; r < 16; ++r) s += lossRed[r];
            atomicAdd(out, s * (1.0f / NR));
        }
    }
}

extern "C" void kernel_launch(void* const* d_in, const int* in_sizes, int n_in,
                              void* d_out, int out_size, void* d_ws, size_t ws_size,
                              hipStream_t stream)
{
    const float* img    = (const float*)d_in[0];   // [4096,512]
    const float* txt    = (const float*)d_in[1];   // [4096,512]
    const int*   labels = (const int*)d_in[2];     // [4096]
    float* out = (float*)d_out;

    char* ws = (char*)d_ws;
    unsigned short* K_b    = (unsigned short*)(ws);                        // 32 MiB
    unsigned short* img_b  = (unsigned short*)(ws + ((size_t)32 << 20));   //  4 MiB
    unsigned short* txt_b  = (unsigned short*)(ws + ((size_t)36 << 20));   //  4 MiB
    unsigned short* vtxtT  = (unsigned short*)(ws + ((size_t)40 << 20));   //  4 MiB
    unsigned short* uimgT  = (unsigned short*)(ws + ((size_t)44 << 20));   //  4 MiB
    unsigned short* NB2T   = (unsigned short*)(ws + ((size_t)48 << 20));   //  4 MiB
    unsigned short* NB_b   = (unsigned short*)(ws + ((size_t)52 << 20));   //  4 MiB
    unsigned short* AmatT  = (unsigned short*)(ws + ((size_t)56 << 20));   // 0.5 MiB
    float* Amat_f          = (float*)(ws + ((size_t)57 << 20));            //  1 MiB
    float* Dacc            = (float*)(ws + ((size_t)58 << 20));            //  8 MiB
    float* Pbuf            = Dacc;   // alias: Dacc dead once amat_update ran
    float* u               = (float*)(ws + ((size_t)66 << 20));
    float* v               = (float*)(ws + ((size_t)66 << 20) + (16 << 10));
    int*   bar             = (int*)  (ws + ((size_t)66 << 20) + (32 << 10));  // 17 lines x 128 B

    const dim3 blk(256);
    const dim3 gNN(32, 32);
    const dim3 gG2(32, 4);
    const dim3 gG3(4, 4, 8);
    const dim3 gG4(4, 32);
    const dim3 gST(64, 8);

    convert_bf16<<<2048, blk, 0, stream>>>(img, img_b, NR * DD / 4);
    convert_bf16<<<2048, blk, 0, stream>>>(txt, txt_b, NR * DD / 4);
    hipMemsetAsync(bar, 0, 4096, stream);
    hipMemsetAsync(out, 0, sizeof(float), stream);

    // K = exp(100 * img.txt^T); u = 1/rowsum (exact row softmax); A = I
    ntgemm<1><<<gNN, blk, 0, stream>>>(img_b, txt_b, K_b, DD, DD, NR, 100.0f);
    fill_kernel<<<16, blk, 0, stream>>>(v, NR, 1.0f);
    rowmv_recip_b<<<NR / 4, blk, 0, stream>>>(K_b, v, u);
    init_amat<<<DD * DD / 256, blk, 0, stream>>>(Amat_f);

    for (int it = 0; it < 5; ++it) {
        scale_transpose<<<gST, blk, 0, stream>>>(txt, v, vtxtT);
        ntgemm<0><<<gG2, blk, 0, stream>>>(vtxtT, K_b, NB2T, NR, NR, NR, 0.f);
        scale_transpose<<<gST, blk, 0, stream>>>(img, u, uimgT);
        ntgemm<2><<<gG3, blk, 0, stream>>>(uimgT, NB2T, Dacc, NR, NR / 8, DD, 0.f);
        amat_update<<<dim3(8, 8), blk, 0, stream>>>(Dacc, Amat_f, AmatT);
        ntgemm<0><<<gG4, blk, 0, stream>>>(img_b, AmatT, NB_b, DD, DD, DD, 0.f);
        ntgemm<1><<<gNN, blk, 0, stream>>>(NB_b, txt_b, K_b, DD, DD, NR, -1.0f);

        // cooperative persistent sinkhorn (10 gens/launch, hierarchical barrier)
        int baseGen = it * 10;
        int doLoss  = (it == 4) ? 1 : 0;
        const unsigned short* Kc = K_b;
        const int* lab = labels;
        void* args[] = { (void*)&Kc, (void*)&u, (void*)&v, (void*)&Pbuf,
                         (void*)&bar, (void*)&lab, (void*)&out,
                         (void*)&baseGen, (void*)&doLoss };
        hipLaunchCooperativeKernel((void*)sinkhorn5, dim3(256), blk, args, 0, stream);
    }
}